// Round 16
// baseline (32.642 us; speedup 1.0000x reference)
//
#include <hip/hip_runtime.h>
#include <cstdint>

#define T_STEPS 2048
#define NFEAT   2048
#define A_POS 0.05f
#define A_NEG 0.05f
#define LR    0.01f
#define DECAY 0.60653065971263342f   // exp(-1/2), tau_pos == tau_neg == 2
#define QSCALE 1000.0f               // |kin| <= 0.12707 -> |q| <= 127 (fits i8)
#define OUTSCALE 1.0e-5f             // LR / QSCALE
#define KSTRIDE ((size_t)8 * NFEAT * 16)   // kinT bytes per BK=128 K-step

typedef unsigned char u8;
typedef int i32x4 __attribute__((ext_vector_type(4)));

#define AS1 __attribute__((address_space(1)))
#define AS3 __attribute__((address_space(3)))

__device__ __forceinline__ uint32_t s8(float a, float b, float c, float d) {
  return (uint32_t)(__float2int_rn(a) | (__float2int_rn(b) << 8) |
                    (__float2int_rn(c) << 16) | (__float2int_rn(d) << 24));
}

// ---------------------------------------------------------------------------
// Prep (R10 logic verbatim; ONLY kinT's store layout changed):
//  blocks [0,256):     STDP scans -> kinT k-block-major: [t/16][j][16] i8
//  blocks [256,1280):  transpose  -> outT[i][t] i8 (binary, exact)
// k-block-major kinT makes the GEMM's per-wave B fragments 256B-contiguous
// -> B can be loaded global->VGPR directly (fixes R13's scatter failure).
// Scan store stays coalesced: consecutive tid -> consecutive 16B chunks.
// ---------------------------------------------------------------------------
#define TC   64
#define HALO 32
__global__ __launch_bounds__(256) void prep_kernel(
    const float* __restrict__ in, const float* __restrict__ outspk,
    u8* __restrict__ kinT, u8* __restrict__ outT) {
  __shared__ union {
    float kv[TC][256];    // scan role: 64 KB
    float tile[64][65];   // transpose role: 16.6 KB
  } sm;
  const int bx = blockIdx.x;
  const int tid = threadIdx.x;

  if (bx < 256) {
    // ---- scan role: thread owns feature column j, t-chunk chn ----
    const int jb  = (bx & 7) * 256;
    const int j   = jb + tid;
    const int chn = bx >> 3;              // 0..31
    const int t0  = chn * TC;
    const float d = DECAY;
    const float* cp = in + j;

    // backward halo carry (uniform branch; edge chunk skips)
    float bh = 0.f;
    if (chn < 31) {
#pragma unroll
      for (int u = HALO - 1; u >= 0; --u)
        bh = cp[(size_t)(t0 + TC + u) * NFEAT] + d * bh;
    }
    // main backward scan -> LDS: kv[u] = B[t0+u] (includes row t0+u)
    {
      float b = bh;
#pragma unroll
      for (int u = TC - 1; u >= 0; --u) {
        b = cp[(size_t)(t0 + u) * NFEAT] + d * b;
        sm.kv[u][tid] = b;
      }
    }
    // forward halo carry
    float f = 0.f;
    if (chn > 0) {
#pragma unroll
      for (int u = 0; u < HALO; ++u)
        f = d * (f + cp[(size_t)(t0 - HALO + u) * NFEAT]);
    }
    // forward pass: combine, quantize; reconstruct in[t] from kv to advance f
    uint32_t qw[TC / 4];
    float cur = sm.kv[0][tid];
#pragma unroll
    for (int u = 0; u < TC; ++u) {
      float nxt = (u < TC - 1) ? sm.kv[u + 1][tid] : bh;
      float K = A_POS * f - A_NEG * cur;
      f = d * (f + (cur - d * nxt));        // in[t0+u] = kv[u] - d*kv[u+1]
      int q = __float2int_rn(K * QSCALE) & 255;
      uint32_t qs = (uint32_t)q << ((u & 3) * 8);
      qw[u >> 2] = (u & 3) ? (qw[u >> 2] | qs) : qs;
      cur = nxt;
    }
    // k-block-major store: chunk g -> kinT[(t0/16+g)*NFEAT*16 + j*16]
#pragma unroll
    for (int g = 0; g < 4; ++g)
      *(uint4*)&kinT[((size_t)(t0 / 16 + g) * NFEAT + j) * 16] =
          make_uint4(qw[4 * g], qw[4 * g + 1], qw[4 * g + 2], qw[4 * g + 3]);
  } else {
    // ---- transpose role: out_spk [t][i] fp32 -> outT [i][t] i8 ----
    const int bb = bx - 256;
    const int t0 = (bb & 31) * 64;
    const int i0 = (bb >> 5) * 64;
#pragma unroll
    for (int p = 0; p < 4; ++p) {            // float4-vectorized tile load
      int idx = p * 256 + tid;               // 0..1023
      int r = idx >> 4, c4 = idx & 15;
      float4 v = *(const float4*)&outspk[(size_t)(t0 + r) * NFEAT + i0 + c4 * 4];
      sm.tile[r][c4 * 4 + 0] = v.x;
      sm.tile[r][c4 * 4 + 1] = v.y;
      sm.tile[r][c4 * 4 + 2] = v.z;
      sm.tile[r][c4 * 4 + 3] = v.w;
    }
    __syncthreads();
    const int il = tid >> 2, tc = tid & 3;   // thread: 16 t for one i
    uint4 w;
    w.x = s8(sm.tile[tc*16+ 0][il], sm.tile[tc*16+ 1][il], sm.tile[tc*16+ 2][il], sm.tile[tc*16+ 3][il]);
    w.y = s8(sm.tile[tc*16+ 4][il], sm.tile[tc*16+ 5][il], sm.tile[tc*16+ 6][il], sm.tile[tc*16+ 7][il]);
    w.z = s8(sm.tile[tc*16+ 8][il], sm.tile[tc*16+ 9][il], sm.tile[tc*16+10][il], sm.tile[tc*16+11][il]);
    w.w = s8(sm.tile[tc*16+12][il], sm.tile[tc*16+13][il], sm.tile[tc*16+14][il], sm.tile[tc*16+15][il]);
    *(uint4*)&outT[(size_t)(i0 + il) * T_STEPS + t0 + tc * 16] = w;
  }
}

// ---------------------------------------------------------------------------
// i8 GEMM: C = W + 1e-5 * A.Bt, tile 128x128, BK=128, 512 threads,
// in-block K-split (2ks x 2wm x 2wn, 64x64 wave-tiles).
// vs R10: B frags are single-consumer -> loaded global->VGPR directly
// (COALESCED via k-block-major kinT; fixes R13's scatter). LDS stages A only
// (3-buf ring of 16 KB in a 64 KB block, prefetch dist 2, asm vmcnt(6));
// per-K-step LDS traffic 96 -> 48 KB, gload_lds halved. Compiler auto-waits
// cover the B regs. R10 exchange epilogue verbatim (64 KB available).
// ---------------------------------------------------------------------------
__global__ __launch_bounds__(512, 1) void stdp_gemm_kernel(
    const u8* __restrict__ A, const u8* __restrict__ Bk,
    const float* __restrict__ W, float* __restrict__ C) {
  __shared__ u8 lds[4][16384];        // bufs 0..2 = A ring; all 64 KB = exchange
  const int tid = threadIdx.x;
  const int lane = tid & 63, wave = tid >> 6;
  const int ks = wave >> 2;                    // k-slice (0: k<64, 1: k>=64)
  const int wm = (wave >> 1) & 1, wn = wave & 1;  // 2x2 grid of 64x64 tiles
  const int lr = lane & 15, lk = lane >> 4;

  // XCD-aware decode: 256 blocks -> 16x16 tiles, each XCD a 4x8 chunk
  const int bid = blockIdx.x;
  const int xcd = bid & 7, q = bid >> 3;       // q in [0,32)
  const int it = (xcd >> 1) * 4 + (q >> 3);    // 0..15
  const int jt = (xcd & 1) * 8 + (q & 7);      // 0..15
  const int i0 = it * 128, j0 = jt * 128;

  i32x4 acc[4][4];
#pragma unroll
  for (int m = 0; m < 4; ++m)
#pragma unroll
    for (int n = 0; n < 4; ++n) acc[m][n] = (i32x4){0, 0, 0, 0};

  // A-stage: 128x128 i8 = 1024 16B chunks; 512 threads -> 2 each
  auto stageA = [&](int buf, int kt) {
    const int k0 = kt * 128;
#pragma unroll
    for (int p = 0; p < 2; ++p) {
      int ch = p * 512 + tid;                  // 0..1023
      int r = ch >> 3, c = ch & 7;
      int csw = c ^ (r & 7);                   // inverse-swizzle the SOURCE
      __builtin_amdgcn_global_load_lds(
          (const AS1 void*)(A + (size_t)(i0 + r) * T_STEPS + k0 + csw * 16),
          (AS3 void*)((char*)&lds[buf][0] + (p * 512 + wave * 64) * 16),
          16, 0, 0);
    }
  };

  // B bases: this wave's private columns, coalesced in k-block-major layout
  const u8* bp0 = Bk + ((size_t)(ks * 4 + lk) * NFEAT + (j0 + wn * 64 + lr)) * 16;
  const u8* bp1 = bp0 + 16 * 16;               // n-stride: 16 j rows x 16 B
  const u8* bp2 = bp0 + 32 * 16;
  const u8* bp3 = bp0 + 48 * 16;

  i32x4 b0_0, b0_1, b0_2, b0_3;                // B reg buffer 0
  i32x4 b1_0, b1_1, b1_2, b1_3;                // B reg buffer 1

#define LOADB(BUF, KT) do {                     \
    size_t o_ = (size_t)(KT) * KSTRIDE;         \
    BUF##_0 = *(const i32x4*)(bp0 + o_);        \
    BUF##_1 = *(const i32x4*)(bp1 + o_);        \
    BUF##_2 = *(const i32x4*)(bp2 + o_);        \
    BUF##_3 = *(const i32x4*)(bp3 + o_);        \
  } while (0)

  const int NKT = T_STEPS / 128;   // 16
  float wv[4][4][4];               // W prefetch (waves 4-7, last K-step)

  stageA(0, 0);
  stageA(1, 1);
  LOADB(b0, 0);                    // issue AFTER stages: retirement order A0,A1,B0

#define GEMM_ITER(KT, BC, BN) do {                                            \
    if ((KT) < NKT - 1) asm volatile("s_waitcnt vmcnt(6)" ::: "memory");      \
    else                asm volatile("s_waitcnt vmcnt(4)" ::: "memory");      \
    __builtin_amdgcn_s_barrier();                                             \
    asm volatile("" ::: "memory");                                            \
    if ((KT) + 2 < NKT) stageA(((KT) + 2) % 3, (KT) + 2);                     \
    if ((KT) + 1 < NKT) { LOADB(BN, (KT) + 1); }                              \
    if ((KT) == NKT - 1 && wave >= 4) {                                       \
      _Pragma("unroll")                                                       \
      for (int m = 0; m < 4; ++m)                                             \
        _Pragma("unroll")                                                     \
        for (int n = 0; n < 4; ++n) {                                         \
          int col = j0 + wn * 64 + n * 16 + lr;                               \
          int row = i0 + wm * 64 + m * 16 + lk * 4;                           \
          _Pragma("unroll")                                                   \
          for (int r = 0; r < 4; ++r)                                         \
            wv[m][n][r] = W[(size_t)(row + r) * NFEAT + col];                 \
        }                                                                     \
    }                                                                         \
    i32x4 af[4];                                                              \
    _Pragma("unroll")                                                         \
    for (int m = 0; m < 4; ++m) {                                             \
      int row = wm * 64 + m * 16 + lr;                                        \
      int cg = (ks * 4 + lk) ^ (row & 7);                                     \
      af[m] = *(const i32x4*)((const char*)&lds[(KT) % 3][0] +                \
                              row * 128 + cg * 16);                           \
    }                                                                         \
    __builtin_amdgcn_s_setprio(1);                                            \
    _Pragma("unroll")                                                         \
    for (int m = 0; m < 4; ++m) {                                             \
      acc[m][0] = __builtin_amdgcn_mfma_i32_16x16x64_i8(af[m], BC##_0, acc[m][0], 0, 0, 0); \
      acc[m][1] = __builtin_amdgcn_mfma_i32_16x16x64_i8(af[m], BC##_1, acc[m][1], 0, 0, 0); \
      acc[m][2] = __builtin_amdgcn_mfma_i32_16x16x64_i8(af[m], BC##_2, acc[m][2], 0, 0, 0); \
      acc[m][3] = __builtin_amdgcn_mfma_i32_16x16x64_i8(af[m], BC##_3, acc[m][3], 0, 0, 0); \
    }                                                                         \
    __builtin_amdgcn_s_setprio(0);                                            \
  } while (0)

  for (int kp = 0; kp < NKT / 2; ++kp) {
    GEMM_ITER(2 * kp,     b0, b1);
    GEMM_ITER(2 * kp + 1, b1, b0);
  }
#undef GEMM_ITER
#undef LOADB

  // ---- k-slice combine via LDS exchange (R10 verbatim; ring retired) ----
  __syncthreads();                    // all MFMA + last LDS reads done
  int* xch = (int*)&lds[0][0];        // 4 waves x 16 KB = 64 KB exactly
  if (wave < 4) {
#pragma unroll
    for (int m = 0; m < 4; ++m)
#pragma unroll
      for (int n = 0; n < 4; ++n)
        *(i32x4*)(xch + wave * 4096 + (m * 4 + n) * 256 + lane * 4) = acc[m][n];
  }
  __syncthreads();
  if (wave >= 4) {
    const int w2 = wave - 4;          // partner with same (wm,wn), ks=0
#pragma unroll
    for (int m = 0; m < 4; ++m)
#pragma unroll
      for (int n = 0; n < 4; ++n) {
        i32x4 part = *(const i32x4*)(xch + w2 * 4096 + (m * 4 + n) * 256 + lane * 4);
        acc[m][n] += part;
        int col = j0 + wn * 64 + n * 16 + lr;
#pragma unroll
        for (int r = 0; r < 4; ++r) {
          int row = i0 + wm * 64 + m * 16 + lk * 4 + r;
          C[(size_t)row * NFEAT + col] = wv[m][n][r] + OUTSCALE * (float)acc[m][n][r];
        }
      }
  }
}

extern "C" void kernel_launch(void* const* d_in, const int* in_sizes, int n_in,
                              void* d_out, int out_size, void* d_ws, size_t ws_size,
                              hipStream_t stream) {
  const float* weight  = (const float*)d_in[0];
  const float* in_spk  = (const float*)d_in[1];
  const float* out_spk = (const float*)d_in[2];
  float* out = (float*)d_out;

  u8* kinT = (u8*)d_ws;                                   // 4 MB i8, kblk-major
  u8* outT = kinT + (size_t)T_STEPS * NFEAT;              // 4 MB i8 [O][T]

  prep_kernel<<<dim3(1280), 256, 0, stream>>>(in_spk, out_spk, kinT, outT);

  stdp_gemm_kernel<<<dim3(256), 512, 0, stream>>>(outT, kinT, weight, out);
}

// Round 17
// 29.662 us; speedup vs baseline: 1.1005x; 1.1005x over previous
//
#include <hip/hip_runtime.h>
#include <cstdint>

#define T_STEPS 2048
#define NFEAT   2048
#define A_POS 0.05f
#define A_NEG 0.05f
#define LR    0.01f
#define DECAY 0.60653065971263342f   // exp(-1/2), tau_pos == tau_neg == 2
#define QSCALE 1000.0f               // |kin| <= 0.12707 -> |q| <= 127 (fits i8)
#define OUTSCALE 1.0e-5f             // LR / QSCALE

typedef unsigned char u8;
typedef int i32x4 __attribute__((ext_vector_type(4)));

#define AS1 __attribute__((address_space(1)))
#define AS3 __attribute__((address_space(3)))

__device__ __forceinline__ uint32_t s8(float a, float b, float c, float d) {
  return (uint32_t)(__float2int_rn(a) | (__float2int_rn(b) << 8) |
                    (__float2int_rn(c) << 16) | (__float2int_rn(d) << 24));
}

// ---------------------------------------------------------------------------
// Prep (R10 champion, measured-best):
//  blocks [0,256):     STDP scans -> kinT[j][t] i8 (fixed-point, x1000)
//  blocks [256,1280):  transpose  -> outT[i][t] i8 (binary, exact)
// Backward-scan array kv lives in LDS (column-per-thread) -> no scratch spill.
// ---------------------------------------------------------------------------
#define TC   64
#define HALO 32   // decay^32 = 1.1e-7 -> truncation ~1.4e-8 << i8 quantum
__global__ __launch_bounds__(256) void prep_kernel(
    const float* __restrict__ in, const float* __restrict__ outspk,
    u8* __restrict__ kinT, u8* __restrict__ outT) {
  __shared__ union {
    float kv[TC][256];    // scan role: 64 KB
    float tile[64][65];   // transpose role: 16.6 KB
  } sm;
  const int bx = blockIdx.x;
  const int tid = threadIdx.x;

  if (bx < 256) {
    // ---- scan role: thread owns feature column j, t-chunk chn ----
    const int jb  = (bx & 7) * 256;
    const int j   = jb + tid;
    const int chn = bx >> 3;              // 0..31
    const int t0  = chn * TC;
    const float d = DECAY;
    const float* cp = in + j;

    // backward halo carry (uniform branch; edge chunk skips)
    float bh = 0.f;
    if (chn < 31) {
#pragma unroll
      for (int u = HALO - 1; u >= 0; --u)
        bh = cp[(size_t)(t0 + TC + u) * NFEAT] + d * bh;
    }
    // main backward scan -> LDS: kv[u] = B[t0+u] (includes row t0+u)
    {
      float b = bh;
#pragma unroll
      for (int u = TC - 1; u >= 0; --u) {
        b = cp[(size_t)(t0 + u) * NFEAT] + d * b;
        sm.kv[u][tid] = b;
      }
    }
    // forward halo carry
    float f = 0.f;
    if (chn > 0) {
#pragma unroll
      for (int u = 0; u < HALO; ++u)
        f = d * (f + cp[(size_t)(t0 - HALO + u) * NFEAT]);
    }
    // forward pass: combine, quantize; reconstruct in[t] from kv to advance f
    uint32_t qw[TC / 4];
    float cur = sm.kv[0][tid];
#pragma unroll
    for (int u = 0; u < TC; ++u) {
      float nxt = (u < TC - 1) ? sm.kv[u + 1][tid] : bh;
      float K = A_POS * f - A_NEG * cur;
      f = d * (f + (cur - d * nxt));        // in[t0+u] = kv[u] - d*kv[u+1]
      int q = __float2int_rn(K * QSCALE) & 255;
      uint32_t qs = (uint32_t)q << ((u & 3) * 8);
      qw[u >> 2] = (u & 3) ? (qw[u >> 2] | qs) : qs;
      cur = nxt;
    }
    // thread owns a full 64B line of kinT: 4 x 16B contiguous stores
    uint4* dst = (uint4*)&kinT[(size_t)j * T_STEPS + t0];
#pragma unroll
    for (int g = 0; g < 4; ++g)
      dst[g] = make_uint4(qw[4 * g], qw[4 * g + 1], qw[4 * g + 2], qw[4 * g + 3]);
  } else {
    // ---- transpose role: out_spk [t][i] fp32 -> outT [i][t] i8 ----
    const int bb = bx - 256;
    const int t0 = (bb & 31) * 64;
    const int i0 = (bb >> 5) * 64;
#pragma unroll
    for (int p = 0; p < 4; ++p) {            // float4-vectorized tile load
      int idx = p * 256 + tid;               // 0..1023
      int r = idx >> 4, c4 = idx & 15;
      float4 v = *(const float4*)&outspk[(size_t)(t0 + r) * NFEAT + i0 + c4 * 4];
      sm.tile[r][c4 * 4 + 0] = v.x;
      sm.tile[r][c4 * 4 + 1] = v.y;
      sm.tile[r][c4 * 4 + 2] = v.z;
      sm.tile[r][c4 * 4 + 3] = v.w;
    }
    __syncthreads();
    const int il = tid >> 2, tc = tid & 3;   // thread: 16 t for one i
    uint4 w;
    w.x = s8(sm.tile[tc*16+ 0][il], sm.tile[tc*16+ 1][il], sm.tile[tc*16+ 2][il], sm.tile[tc*16+ 3][il]);
    w.y = s8(sm.tile[tc*16+ 4][il], sm.tile[tc*16+ 5][il], sm.tile[tc*16+ 6][il], sm.tile[tc*16+ 7][il]);
    w.z = s8(sm.tile[tc*16+ 8][il], sm.tile[tc*16+ 9][il], sm.tile[tc*16+10][il], sm.tile[tc*16+11][il]);
    w.w = s8(sm.tile[tc*16+12][il], sm.tile[tc*16+13][il], sm.tile[tc*16+14][il], sm.tile[tc*16+15][il]);
    *(uint4*)&outT[(size_t)(i0 + il) * T_STEPS + t0 + tc * 16] = w;
  }
}

// ---------------------------------------------------------------------------
// i8 GEMM (R10 champion): C = W + 1e-5 * A.Bt  (i32 exact acc), tile
// 128x128, BK=128, 512 threads. In-block K-split: waves 0-3 k-slice 0,
// waves 4-7 k-slice 1, over a 2x2 grid of 64x64 wave-tiles. 3-buffer
// counted-vmcnt(4) schedule, XOR swizzle (rule 21), LDS exchange epilogue.
// ---------------------------------------------------------------------------
__global__ __launch_bounds__(512, 1) void stdp_gemm_kernel(
    const u8* __restrict__ A, const u8* __restrict__ B,
    const float* __restrict__ W, float* __restrict__ C) {
  __shared__ u8 lds[3][32768];        // per buf: A 16 KB @0, B 16 KB @16384
  const int tid = threadIdx.x;
  const int lane = tid & 63, wave = tid >> 6;
  const int ks = wave >> 2;                    // k-slice (0: k<64, 1: k>=64)
  const int wm = (wave >> 1) & 1, wn = wave & 1;  // 2x2 grid of 64x64 tiles
  const int lr = lane & 15, lk = lane >> 4;

  // XCD-aware decode: 256 blocks -> 16x16 tiles, each XCD a 4x8 chunk
  const int bid = blockIdx.x;
  const int xcd = bid & 7, q = bid >> 3;       // q in [0,32)
  const int it = (xcd >> 1) * 4 + (q >> 3);    // 0..15
  const int jt = (xcd & 1) * 8 + (q & 7);      // 0..15
  const int i0 = it * 128, j0 = jt * 128;

  i32x4 acc[4][4];
#pragma unroll
  for (int m = 0; m < 4; ++m)
#pragma unroll
    for (int n = 0; n < 4; ++n) acc[m][n] = (i32x4){0, 0, 0, 0};

  // per stage: each thread-slot issues 2 A + 2 B gload_lds (16B = 16 i8)
  auto stage = [&](int buf, int kt) {
    const int k0 = kt * 128;
#pragma unroll
    for (int p = 0; p < 2; ++p) {
      int ch = p * 512 + tid;                  // 0..1023
      int r = ch >> 3, c = ch & 7;
      int csw = c ^ (r & 7);                   // inverse-swizzle the SOURCE
      __builtin_amdgcn_global_load_lds(
          (const AS1 void*)(A + (size_t)(i0 + r) * T_STEPS + k0 + csw * 16),
          (AS3 void*)((char*)&lds[buf][0] + (p * 512 + wave * 64) * 16),
          16, 0, 0);
    }
#pragma unroll
    for (int p = 0; p < 2; ++p) {
      int ch = p * 512 + tid;
      int r = ch >> 3, c = ch & 7;
      int csw = c ^ (r & 7);
      __builtin_amdgcn_global_load_lds(
          (const AS1 void*)(B + (size_t)(j0 + r) * T_STEPS + k0 + csw * 16),
          (AS3 void*)((char*)&lds[buf][16384] + (p * 512 + wave * 64) * 16),
          16, 0, 0);
    }
  };

  stage(0, 0);
  stage(1, 1);                     // 8 load-instrs in flight per wave

  float wv[4][4][4];               // W prefetch target (waves 4-7, last step)

  const int NKT = T_STEPS / 128;   // 16
  int rb = 0;
  for (int kt = 0; kt < NKT; ++kt) {
    if (kt < NKT - 1) asm volatile("s_waitcnt vmcnt(4)" ::: "memory");
    else              asm volatile("s_waitcnt vmcnt(0)" ::: "memory");
    __builtin_amdgcn_s_barrier();   // tile kt fully in LDS for all waves
    asm volatile("" ::: "memory");

    if (kt + 2 < NKT) {             // overwrites buffer consumed at kt-1
      int sb = rb + 2; if (sb >= 3) sb -= 3;
      stage(sb, kt + 2);
    }

    if (kt == NKT - 1 && wave >= 4) {  // vm queue idle: free W prefetch
#pragma unroll
      for (int m = 0; m < 4; ++m)
#pragma unroll
        for (int n = 0; n < 4; ++n) {
          int col = j0 + wn * 64 + n * 16 + lr;
          int row = i0 + wm * 64 + m * 16 + lk * 4;
#pragma unroll
          for (int r = 0; r < 4; ++r)
            wv[m][n][r] = W[(size_t)(row + r) * NFEAT + col];
        }
    }

    {
      i32x4 af[4], bf[4];
#pragma unroll
      for (int m = 0; m < 4; ++m) {
        int row = wm * 64 + m * 16 + lr;
        int cg = (ks * 4 + lk) ^ (row & 7);    // swizzled read
        af[m] = *(const i32x4*)((const char*)&lds[rb][0] + row * 128 + cg * 16);
      }
#pragma unroll
      for (int n = 0; n < 4; ++n) {
        int row = wn * 64 + n * 16 + lr;
        int cg = (ks * 4 + lk) ^ (row & 7);
        bf[n] = *(const i32x4*)((const char*)&lds[rb][16384] + row * 128 + cg * 16);
      }
      __builtin_amdgcn_s_setprio(1);
#pragma unroll
      for (int m = 0; m < 4; ++m)
#pragma unroll
        for (int n = 0; n < 4; ++n)
          acc[m][n] = __builtin_amdgcn_mfma_i32_16x16x64_i8(af[m], bf[n], acc[m][n], 0, 0, 0);
      __builtin_amdgcn_s_setprio(0);
    }
    rb = (rb == 2) ? 0 : rb + 1;
  }

  // ---- combine k-slices via LDS exchange (staging buffers are retired) ----
  __syncthreads();                    // all MFMA + last LDS reads done
  int* xch = (int*)&lds[0][0];        // 64 KB needed, 96 KB available
  if (wave < 4) {
#pragma unroll
    for (int m = 0; m < 4; ++m)
#pragma unroll
      for (int n = 0; n < 4; ++n)
        *(i32x4*)(xch + wave * 4096 + (m * 4 + n) * 256 + lane * 4) = acc[m][n];
  }
  __syncthreads();
  if (wave >= 4) {
    const int w2 = wave - 4;          // partner with same (wm,wn), ks=0
#pragma unroll
    for (int m = 0; m < 4; ++m)
#pragma unroll
      for (int n = 0; n < 4; ++n) {
        i32x4 part = *(const i32x4*)(xch + w2 * 4096 + (m * 4 + n) * 256 + lane * 4);
        acc[m][n] += part;
        int col = j0 + wn * 64 + n * 16 + lr;
#pragma unroll
        for (int r = 0; r < 4; ++r) {
          int row = i0 + wm * 64 + m * 16 + lk * 4 + r;
          C[(size_t)row * NFEAT + col] = wv[m][n][r] + OUTSCALE * (float)acc[m][n][r];
        }
      }
  }
}

extern "C" void kernel_launch(void* const* d_in, const int* in_sizes, int n_in,
                              void* d_out, int out_size, void* d_ws, size_t ws_size,
                              hipStream_t stream) {
  const float* weight  = (const float*)d_in[0];
  const float* in_spk  = (const float*)d_in[1];
  const float* out_spk = (const float*)d_in[2];
  float* out = (float*)d_out;

  u8* kinT = (u8*)d_ws;                                   // 4 MB i8 [I][T]
  u8* outT = kinT + (size_t)T_STEPS * NFEAT;              // 4 MB i8 [O][T]

  prep_kernel<<<dim3(1280), 256, 0, stream>>>(in_spk, out_spk, kinT, outT);

  stdp_gemm_kernel<<<dim3(256), 512, 0, stream>>>(outT, kinT, weight, out);
}